// Round 20
// baseline (214.454 us; speedup 1.0000x reference)
//
#include <hip/hip_runtime.h>

typedef __attribute__((ext_vector_type(8))) _Float16 half8;
typedef __attribute__((ext_vector_type(4))) float f32x4;

#define BATCH  4
#define SLEN   2048
#define DMODEL 2048
#define NKV    8
#define GRP    4
#define DH     64
#define QKV    1536
#define KVDIM  512
#define MROWS  (BATCH * SLEN)   // 8192

// ---- fp16 helper (RNE via hardware cvt) ------------------------------------
__device__ __forceinline__ unsigned short f2h(float f) {
    union { _Float16 h; unsigned short u; } cv;
    cv.h = (_Float16)f;
    return cv.u;
}

// ---- async global->LDS, 16B per lane ---------------------------------------
__device__ __forceinline__ void gl16(const void* g, void* l) {
    __builtin_amdgcn_global_load_lds(
        (const __attribute__((address_space(1))) void*)g,
        (__attribute__((address_space(3))) void*)l, 16, 0, 0);
}

typedef __attribute__((ext_vector_type(4))) short short4v;
union U64S4 { unsigned long long u; short4v s; };

// ---------------------------------------------------------------------------
// Kernel 1 (fused pack + transpose + fp16): wcatT[c][d], c = mat*512+n*64+h.
// ---------------------------------------------------------------------------
__global__ __launch_bounds__(256) void k_packT(const float* __restrict__ wq,
                                               const float* __restrict__ wk,
                                               const float* __restrict__ wv,
                                               unsigned short* __restrict__ outT) {
    __shared__ float T[64][65];
    const int d0 = blockIdx.x * 64;
    const int ct = blockIdx.y;               // 0..23
    const int mat = ct >> 3, n = ct & 7;
    const int tr = threadIdx.x >> 6, tc = threadIdx.x & 63;
#pragma unroll
    for (int i = 0; i < 16; ++i) {
        int row = tr + i * 4;
        float v;
        if (mat == 0) {
            v = 0.0f;
#pragma unroll
            for (int g = 0; g < GRP; ++g)
                v += wq[((size_t)(n * GRP + g) * DMODEL + d0 + row) * DH + tc];
        } else if (mat == 1) {
            v = wk[((size_t)n * DMODEL + d0 + row) * DH + tc];
        } else {
            v = wv[((size_t)n * DMODEL + d0 + row) * DH + tc];
        }
        T[row][tc] = v;
    }
    __syncthreads();
    const int rr = tc;
#pragma unroll
    for (int i = 0; i < 16; ++i) {
        int cc = tr + i * 4;
        outT[(size_t)(mat * 512 + n * 64 + cc) * DMODEL + d0 + rr] = f2h(T[rr][cc]);
    }
}

// ---------------------------------------------------------------------------
// Kernel 2: transpose + fp16 convert (W_O).
// ---------------------------------------------------------------------------
__global__ __launch_bounds__(256) void k_transconv_h(const float* __restrict__ in,
                                                     unsigned short* __restrict__ outT,
                                                     int R, int C) {
    __shared__ float T[64][65];
    const int r0 = blockIdx.x * 64, c0 = blockIdx.y * 64;
    const int tr = threadIdx.x >> 6, tc = threadIdx.x & 63;
#pragma unroll
    for (int i = 0; i < 16; ++i)
        T[tr + i * 4][tc] = in[(size_t)(r0 + tr + i * 4) * C + c0 + tc];
    __syncthreads();
    const int rr = tc;
#pragma unroll
    for (int i = 0; i < 16; ++i) {
        int cc = tr + i * 4;
        outT[(size_t)(c0 + cc) * R + r0 + rr] = f2h(T[rr][cc]);
    }
}

// ---------------------------------------------------------------------------
// fp16 staging via gl16 (R16-verified swizzle: dest linear, source
// inverse-swizzled c^(row&7) on 128B rows -> 0 bank conflicts).
// ---------------------------------------------------------------------------
__device__ __forceinline__ void stage_rows(const unsigned short* __restrict__ src,
                                           unsigned short* lds, int t, int K,
                                           int k0, int nslots4) {
#pragma unroll
    for (int j = 0; j < 8; ++j) {
        if (j >= nslots4) break;
        int slot = j * 256 + t;
        int row = slot >> 3, blk = slot & 7;
        int c = blk ^ (row & 7);
        gl16(src + (size_t)row * K + k0 + c * 8, lds + slot * 8);
    }
}

// ---------------------------------------------------------------------------
// Kernel 4: fp16 GEMM -> QKV, A = fp32 x converted IN-KERNEL (R20: removes
// the k_convh 96MB round-trip).  A-path: issue 8 global float4 loads at the
// TOP of each K-step (latency hides under 48 MFMAs), cvt + ds_write_b128
// into the same swizzled layout AFTER the MFMA block, then
// vmcnt(0)+lgkmcnt(0) before the barrier.  B-path gl16 unchanged.
// Tile 128x192, grid 64x8 = 512 blocks, 2 blocks/CU (R16-verified shape).
// ---------------------------------------------------------------------------
__global__ __launch_bounds__(256) void k_gemm_qkv(
        const float* __restrict__ Xg, const unsigned short* __restrict__ Bg,
        unsigned short* __restrict__ qk, unsigned short* __restrict__ vT) {
    __shared__ unsigned short A2[2][128 * 64];
    __shared__ unsigned short B2[2][192 * 64];

    const int t = threadIdx.x;
    const size_t m0 = (size_t)blockIdx.x * 128, n0 = (size_t)blockIdx.y * 192;
    const int w = t >> 6, l = t & 63;
    const int wm = (w >> 1) * 64, wn = (w & 1) * 96;
    const int r = l & 15, q = l >> 4;
    f32x4 acc[4][6] = {};
    const int K = DMODEL;
    const int NT = K / 64;

    // A slot geometry (4 slots/thread)
    int arow[4], acol[4];
#pragma unroll
    for (int j = 0; j < 4; ++j) {
        int slot = j * 256 + t;
        arow[j] = slot >> 3;
        acol[j] = ((slot & 7) ^ (arow[j] & 7)) * 8;
    }

#define LOAD_A_REG(av, k0)                                                    \
    _Pragma("unroll") for (int j = 0; j < 4; ++j) {                           \
        const float* src = Xg + (m0 + arow[j]) * (size_t)DMODEL + (k0) + acol[j]; \
        av[j][0] = *(const float4*)src;                                       \
        av[j][1] = *(const float4*)(src + 4);                                 \
    }
#define WRITE_A_LDS(av, buf)                                                  \
    _Pragma("unroll") for (int j = 0; j < 4; ++j) {                           \
        union { unsigned short us[8]; half8 h; } pk;                          \
        pk.us[0] = f2h(av[j][0].x); pk.us[1] = f2h(av[j][0].y);               \
        pk.us[2] = f2h(av[j][0].z); pk.us[3] = f2h(av[j][0].w);               \
        pk.us[4] = f2h(av[j][1].x); pk.us[5] = f2h(av[j][1].y);               \
        pk.us[6] = f2h(av[j][1].z); pk.us[7] = f2h(av[j][1].w);               \
        *(half8*)&A2[buf][(j * 256 + t) * 8] = pk.h;                          \
    }

    {   // prologue: tile 0
        float4 av[4][2];
        LOAD_A_REG(av, 0)
        stage_rows(Bg + n0 * K, B2[0], t, K, 0, 6);
        WRITE_A_LDS(av, 0)
        asm volatile("s_waitcnt vmcnt(0) lgkmcnt(0)" ::: "memory");
        __builtin_amdgcn_s_barrier();
    }
    int cur = 0;
    for (int kt = 0; kt < NT; ++kt) {
        const bool has_next = (kt + 1 < NT);
        float4 av[4][2];
        if (has_next) {
            LOAD_A_REG(av, (kt + 1) * 64)
            stage_rows(Bg + n0 * K, B2[cur ^ 1], t, K, (kt + 1) * 64, 6);
        }
        const unsigned short* Ac = A2[cur];
        const unsigned short* Bc = B2[cur];
        half8 af[4][2], bf[6][2];
#pragma unroll
        for (int i = 0; i < 4; ++i)
#pragma unroll
            for (int ks = 0; ks < 2; ++ks) {
                int ra = wm + i * 16 + r;
                af[i][ks] = *(const half8*)&Ac[ra * 64 + ((((ks << 2) | q) ^ (ra & 7)) << 3)];
            }
#pragma unroll
        for (int j = 0; j < 6; ++j)
#pragma unroll
            for (int ks = 0; ks < 2; ++ks) {
                int rb = wn + j * 16 + r;
                bf[j][ks] = *(const half8*)&Bc[rb * 64 + ((((ks << 2) | q) ^ (rb & 7)) << 3)];
            }
        __builtin_amdgcn_s_setprio(1);
#pragma unroll
        for (int i = 0; i < 4; ++i)
#pragma unroll
            for (int j = 0; j < 6; ++j) {
                acc[i][j] = __builtin_amdgcn_mfma_f32_16x16x32_f16(af[i][0], bf[j][0], acc[i][j], 0, 0, 0);
                acc[i][j] = __builtin_amdgcn_mfma_f32_16x16x32_f16(af[i][1], bf[j][1], acc[i][j], 0, 0, 0);
            }
        __builtin_amdgcn_s_setprio(0);
        if (has_next) {
            WRITE_A_LDS(av, cur ^ 1)
        }
        asm volatile("s_waitcnt vmcnt(0) lgkmcnt(0)" ::: "memory");
        __builtin_amdgcn_s_barrier();
        cur ^= 1;
    }
#undef LOAD_A_REG
#undef WRITE_A_LDS

    // epilogue: per-(i,j) Q/K vs V branch (col boundary 1024 is 16-aligned)
#pragma unroll
    for (int i = 0; i < 4; ++i)
#pragma unroll
        for (int j = 0; j < 6; ++j) {
            int col = (int)n0 + wn + j * 16 + r;
            size_t rowb = m0 + wm + i * 16 + q * 4;
            if (col < 1024) {
#pragma unroll
                for (int e = 0; e < 4; ++e)
                    qk[(rowb + e) * 1024 + col] = f2h(acc[i][j][e]);
            } else {
                int d = col - 1024;
                ushort4 pk;
                pk.x = f2h(acc[i][j][0]); pk.y = f2h(acc[i][j][1]);
                pk.z = f2h(acc[i][j][2]); pk.w = f2h(acc[i][j][3]);
                *(ushort4*)&vT[(size_t)d * MROWS + rowb] = pk;
            }
        }
}

// ---------------------------------------------------------------------------
// Kernel 6: fp16 GEMM 128x128, fp32 C (output projection) — R16-verified.
// ---------------------------------------------------------------------------
__global__ __launch_bounds__(256) void k_gemm_out(
        const unsigned short* __restrict__ Ag, const unsigned short* __restrict__ Bg,
        float* __restrict__ C) {
    __shared__ unsigned short A2[2][128 * 64];
    __shared__ unsigned short B2[2][128 * 64];

    const int t = threadIdx.x;
    const size_t m0 = (size_t)blockIdx.x * 128, n0 = (size_t)blockIdx.y * 128;
    const int w = t >> 6, l = t & 63;
    const int wm = (w >> 1) * 64, wn = (w & 1) * 64;
    const int r = l & 15, q = l >> 4;
    f32x4 acc[4][4] = {};
    const int K = KVDIM;
    const int NT = K / 64;

    stage_rows(Ag + m0 * K, A2[0], t, K, 0, 4);
    stage_rows(Bg + n0 * K, B2[0], t, K, 0, 4);
    asm volatile("s_waitcnt vmcnt(0)" ::: "memory");
    __builtin_amdgcn_s_barrier();
    int cur = 0;
    for (int kt = 0; kt < NT; ++kt) {
        if (kt + 1 < NT) {
            stage_rows(Ag + m0 * K, A2[cur ^ 1], t, K, (kt + 1) * 64, 4);
            stage_rows(Bg + n0 * K, B2[cur ^ 1], t, K, (kt + 1) * 64, 4);
        }
        const unsigned short* Ac = A2[cur];
        const unsigned short* Bc = B2[cur];
        half8 af[4][2], bf[4][2];
#pragma unroll
        for (int i = 0; i < 4; ++i)
#pragma unroll
            for (int ks = 0; ks < 2; ++ks) {
                int ra = wm + i * 16 + r;
                af[i][ks] = *(const half8*)&Ac[ra * 64 + ((((ks << 2) | q) ^ (ra & 7)) << 3)];
                int rb = wn + i * 16 + r;
                bf[i][ks] = *(const half8*)&Bc[rb * 64 + ((((ks << 2) | q) ^ (rb & 7)) << 3)];
            }
        __builtin_amdgcn_s_setprio(1);
#pragma unroll
        for (int i = 0; i < 4; ++i)
#pragma unroll
            for (int j = 0; j < 4; ++j) {
                acc[i][j] = __builtin_amdgcn_mfma_f32_16x16x32_f16(af[i][0], bf[j][0], acc[i][j], 0, 0, 0);
                acc[i][j] = __builtin_amdgcn_mfma_f32_16x16x32_f16(af[i][1], bf[j][1], acc[i][j], 0, 0, 0);
            }
        __builtin_amdgcn_s_setprio(0);
        asm volatile("s_waitcnt vmcnt(0)" ::: "memory");
        __builtin_amdgcn_s_barrier();
        cur ^= 1;
    }

#pragma unroll
    for (int i = 0; i < 4; ++i)
#pragma unroll
        for (int j = 0; j < 4; ++j) {
            int col = (int)n0 + wn + j * 16 + r;
            size_t rowb = m0 + wm + i * 16 + q * 4;
#pragma unroll
            for (int e = 0; e < 4; ++e)
                C[(rowb + e) * DMODEL + col] = acc[i][j][e];
        }
}

// ---------------------------------------------------------------------------
// Kernel 5: fp16 MFMA flash attention — R18-VERIFIED version (KVBLK=128,
// QBLK=64, pairing p 0..15, 2 blocks/CU, batched-PV).  R19's QBLK=128 /
// 1-block/CU variant REVERTED (occupancy loss exposed serial phases;
// attn 70 -> 81 us).
// ---------------------------------------------------------------------------
__global__ __launch_bounds__(256) void k_attn_mfma(
        const unsigned short* __restrict__ qk, const unsigned short* __restrict__ vT,
        unsigned short* __restrict__ zh) {
    __shared__ unsigned short Ks[2][128 * 64];
    __shared__ unsigned short Vs[2][64 * 128];
    __shared__ unsigned short Pt[4 * 128 * 16];   // per-wave 4KB

    const int t  = threadIdx.x;
    const int w  = t >> 6, l = t & 63;
    const int p  = blockIdx.x;        // 0..15 (pair index)
    const int n  = blockIdx.y, b = blockIdx.z;
    const int r  = l & 15, g = l >> 4;
    const int wq0 = w * 16;

#define STAGE_KV(buf, kr0)                                                    \
    _Pragma("unroll") for (int j2 = 0; j2 < 4; ++j2) {                        \
        int s2 = j2 * 256 + t;                                                \
        int rK = s2 >> 3, cK = (s2 & 7) ^ (rK & 7);                           \
        gl16(qk + ((kr0) + rK) * 1024 + 512 + n * 64 + cK * 8,                \
             &Ks[buf][s2 * 8]);                                               \
        int rV = s2 >> 4, cV = (s2 & 15) ^ (rV & 15);                         \
        gl16(vT + (size_t)(n * 64 + rV) * MROWS + (kr0) + cV * 8,             \
             &Vs[buf][s2 * 8]);                                               \
    }

#pragma unroll 1
    for (int seg = 0; seg < 2; ++seg) {
        const int qt = seg ? p : (31 - p);   // heavy tile first
        const int nkt = (qt + 2) >> 1;       // ceil((qt+1)/2) kv-tiles of 128
        const size_t qrow0 = (size_t)(b * SLEN + qt * 64);

        half8 qh[2];
#pragma unroll
        for (int ks = 0; ks < 2; ++ks) {
            size_t off = (qrow0 + wq0 + r) * 1024 + n * 64 + ks * 32 + g * 8;
            qh[ks] = *(const half8*)(qk + off);
#pragma unroll
            for (int e2 = 0; e2 < 8; ++e2) qh[ks][e2] = qh[ks][e2] * (_Float16)0.125f;
        }

        STAGE_KV(0, (size_t)(b * SLEN))
        asm volatile("s_waitcnt vmcnt(0)" ::: "memory");
        __builtin_amdgcn_s_barrier();

        float m_[4], lsum[4];
#pragma unroll
        for (int e = 0; e < 4; ++e) { m_[e] = -3.0e38f; lsum[e] = 0.0f; }
        f32x4 accz[4] = {};

        for (int kt = 0; kt < nkt; ++kt) {
            const int cur = kt & 1;
            if (kt + 1 < nkt) {
                STAGE_KV(cur ^ 1, (size_t)(b * SLEN + (kt + 1) * 128))
            }
            const unsigned short* Ksc = Ks[cur];
            const unsigned short* Vsc = Vs[cur];

            f32x4 s[8] = {};
#pragma unroll
            for (int ct = 0; ct < 8; ++ct)
#pragma unroll
                for (int ks = 0; ks < 2; ++ks) {
                    int row = ct * 16 + r;
                    int off = row * 128 + (((ks * 4 + g) ^ (row & 7)) << 4);
                    half8 kh8 = *(const half8*)((char*)Ksc + off);
                    s[ct] = __builtin_amdgcn_mfma_f32_16x16x32_f16(qh[ks], kh8, s[ct], 0, 0, 0);
                }

            if (kt == nkt - 1) {
#pragma unroll
                for (int ct = 0; ct < 8; ++ct)
#pragma unroll
                    for (int e = 0; e < 4; ++e)
                        if ((kt * 128 + ct * 16 + r) > (qt * 64 + wq0 + g * 4 + e))
                            s[ct][e] = -100000.0f;   // reference IGNORE
            }

            float al[4], nm[4];
#pragma unroll
            for (int e = 0; e < 4; ++e) {
                float pm = fmaxf(fmaxf(fmaxf(s[0][e], s[1][e]), fmaxf(s[2][e], s[3][e])),
                                 fmaxf(fmaxf(s[4][e], s[5][e]), fmaxf(s[6][e], s[7][e])));
                pm = fmaxf(pm, __shfl_xor(pm, 1));
                pm = fmaxf(pm, __shfl_xor(pm, 2));
                pm = fmaxf(pm, __shfl_xor(pm, 4));
                pm = fmaxf(pm, __shfl_xor(pm, 8));
                nm[e] = fmaxf(m_[e], pm);
                al[e] = __expf(m_[e] - nm[e]);
                m_[e] = nm[e];
            }
            {
                int src = (r >> 2) << 4;
                float a0 = __shfl(al[0], src), a1 = __shfl(al[1], src);
                float a2 = __shfl(al[2], src), a3 = __shfl(al[3], src);
                float ax = (r & 1) ? a1 : a0, ay = (r & 1) ? a3 : a2;
                float aq = (r & 2) ? ay : ax;
#pragma unroll
                for (int dt = 0; dt < 4; ++dt) {
                    accz[dt][0] *= aq; accz[dt][1] *= aq;
                    accz[dt][2] *= aq; accz[dt][3] *= aq;
                }
            }

            float ps[4] = {};
#pragma unroll
            for (int ct = 0; ct < 8; ++ct) {
                float p0 = __expf(s[ct][0] - m_[0]);
                float p1 = __expf(s[ct][1] - m_[1]);
                float p2 = __expf(s[ct][2] - m_[2]);
                float p3 = __expf(s[ct][3] - m_[3]);
                ps[0] += p0; ps[1] += p1; ps[2] += p2; ps[3] += p3;
                short4v pk = { (short)f2h(p0), (short)f2h(p1),
                               (short)f2h(p2), (short)f2h(p3) };
                int kv = ct * 16 + r;
                int phys = (kv >> 5) * 32 + (((kv >> 2) & 1) << 4)
                         + (((kv >> 3) & 3) << 2) + (kv & 3);
                *(short4v*)((char*)Pt + w * 4096 + phys * 32 + g * 8) = pk;
            }

#pragma unroll
            for (int e = 0; e < 4; ++e) {
                float rs = ps[e];
                rs += __shfl_xor(rs, 1); rs += __shfl_xor(rs, 2);
                rs += __shfl_xor(rs, 4); rs += __shfl_xor(rs, 8);
                lsum[e] = lsum[e] * al[e] + rs;
            }

            // PV: drain P writes once, issue ALL 8 tr_reads, drain once,
            // then 16 MFMAs.
            asm volatile("s_waitcnt lgkmcnt(0)" ::: "memory");
            __builtin_amdgcn_sched_barrier(0);
            U64S4 tA[4], tB[4];
#pragma unroll
            for (int ks = 0; ks < 4; ++ks) {
                unsigned base = (unsigned)(size_t)((char*)Pt + w * 4096 + ks * 1024) + l * 8;
                asm volatile("ds_read_b64_tr_b16 %0, %1" : "=v"(tA[ks].u) : "v"(base) : "memory");
                asm volatile("ds_read_b64_tr_b16 %0, %1" : "=v"(tB[ks].u) : "v"(base + 512) : "memory");
            }
            asm volatile("s_waitcnt lgkmcnt(0)" ::: "memory");
            __builtin_amdgcn_sched_barrier(0);
#pragma unroll
            for (int ks = 0; ks < 4; ++ks) {
                union { short s[8]; half8 h; } pf;
                pf.s[0] = tA[ks].s[0]; pf.s[1] = tA[ks].s[1];
                pf.s[2] = tA[ks].s[2]; pf.s[3] = tA[ks].s[3];
                pf.s[4] = tB[ks].s[0]; pf.s[5] = tB[ks].s[1];
                pf.s[6] = tB[ks].s[2]; pf.s[7] = tB[ks].s[3];
#pragma unroll
                for (int dt = 0; dt < 4; ++dt) {
                    int d = dt * 16 + r;
                    int off = d * 256 + (((ks * 4 + g) ^ (d & 15)) << 4);
                    half8 vfrag = *(const half8*)((char*)Vsc + off);
                    accz[dt] = __builtin_amdgcn_mfma_f32_16x16x32_f16(vfrag, pf.h, accz[dt], 0, 0, 0);
                }
            }

            asm volatile("s_waitcnt vmcnt(0)" ::: "memory");   // next tile staged
            __builtin_amdgcn_s_barrier();
        }

        int src = (r >> 2) << 4;
        float l0 = __shfl(lsum[0], src), l1 = __shfl(lsum[1], src);
        float l2 = __shfl(lsum[2], src), l3 = __shfl(lsum[3], src);
        float lx = (r & 1) ? l1 : l0, ly = (r & 1) ? l3 : l2;
        float inv = 1.0f / ((r & 2) ? ly : lx);
#pragma unroll
        for (int dt = 0; dt < 4; ++dt) {
            ushort4 h4;
#pragma unroll
            for (int e = 0; e < 4; ++e)
                ((unsigned short*)&h4)[e] = f2h(accz[dt][e] * inv);
            size_t off = (qrow0 + wq0 + r) * 512 + n * 64 + dt * 16 + g * 4;
            *(ushort4*)(zh + off) = h4;
        }
    }
#undef STAGE_KV
}

// ---------------------------------------------------------------------------
// Workspace (bytes, 64 MB region reused):
//   0   : zh fp16 8M (attn output; xh eliminated — x converted in-kernel)
//   32M : qk fp16 16M
//   48M : vT fp16 8M
//   56M : wcatT fp16 6M
//   62M : woT fp16 2M
// ---------------------------------------------------------------------------
extern "C" void kernel_launch(void* const* d_in, const int* in_sizes, int n_in,
                              void* d_out, int out_size, void* d_ws, size_t ws_size,
                              hipStream_t stream) {
    const float* x  = (const float*)d_in[0];
    const float* wq = (const float*)d_in[1];
    const float* wk = (const float*)d_in[2];
    const float* wv = (const float*)d_in[3];
    const float* wo = (const float*)d_in[4];
    float* out = (float*)d_out;

    char* w = (char*)d_ws;
    unsigned short* zh  = (unsigned short*)(w);
    unsigned short* qk  = (unsigned short*)(w + 33554432);
    unsigned short* vT  = (unsigned short*)(w + 50331648);
    unsigned short* wcatT = (unsigned short*)(w + 58720256);
    unsigned short* woT = (unsigned short*)(w + 65011712);

    k_packT<<<dim3(32, 24), 256, 0, stream>>>(wq, wk, wv, wcatT);
    k_transconv_h<<<dim3(8, 32), 256, 0, stream>>>(wo, woT, KVDIM, DMODEL);
    k_gemm_qkv<<<dim3(64, 8), 256, 0, stream>>>(x, wcatT, qk, vT);
    k_attn_mfma<<<dim3(16, NKV, BATCH), 256, 0, stream>>>(qk, vT, zh);
    k_gemm_out<<<dim3(64, 16), 256, 0, stream>>>(zh, woT, out);
}

// Round 21
// 188.552 us; speedup vs baseline: 1.1374x; 1.1374x over previous
//
#include <hip/hip_runtime.h>

typedef __attribute__((ext_vector_type(8))) _Float16 half8;
typedef __attribute__((ext_vector_type(4))) float f32x4;

#define BATCH  4
#define SLEN   2048
#define DMODEL 2048
#define NKV    8
#define GRP    4
#define DH     64
#define QKV    1536
#define KVDIM  512
#define MROWS  (BATCH * SLEN)   // 8192

// ---- fp16 helper (RNE via hardware cvt) ------------------------------------
__device__ __forceinline__ unsigned short f2h(float f) {
    union { _Float16 h; unsigned short u; } cv;
    cv.h = (_Float16)f;
    return cv.u;
}

// ---- async global->LDS, 16B per lane ---------------------------------------
__device__ __forceinline__ void gl16(const void* g, void* l) {
    __builtin_amdgcn_global_load_lds(
        (const __attribute__((address_space(1))) void*)g,
        (__attribute__((address_space(3))) void*)l, 16, 0, 0);
}

typedef __attribute__((ext_vector_type(4))) short short4v;
union U64S4 { unsigned long long u; short4v s; };

// ---------------------------------------------------------------------------
// Kernel 1 (fused pack + transpose + fp16): wcatT[c][d], c = mat*512+n*64+h.
// ---------------------------------------------------------------------------
__global__ __launch_bounds__(256) void k_packT(const float* __restrict__ wq,
                                               const float* __restrict__ wk,
                                               const float* __restrict__ wv,
                                               unsigned short* __restrict__ outT) {
    __shared__ float T[64][65];
    const int d0 = blockIdx.x * 64;
    const int ct = blockIdx.y;               // 0..23
    const int mat = ct >> 3, n = ct & 7;
    const int tr = threadIdx.x >> 6, tc = threadIdx.x & 63;
#pragma unroll
    for (int i = 0; i < 16; ++i) {
        int row = tr + i * 4;
        float v;
        if (mat == 0) {
            v = 0.0f;
#pragma unroll
            for (int g = 0; g < GRP; ++g)
                v += wq[((size_t)(n * GRP + g) * DMODEL + d0 + row) * DH + tc];
        } else if (mat == 1) {
            v = wk[((size_t)n * DMODEL + d0 + row) * DH + tc];
        } else {
            v = wv[((size_t)n * DMODEL + d0 + row) * DH + tc];
        }
        T[row][tc] = v;
    }
    __syncthreads();
    const int rr = tc;
#pragma unroll
    for (int i = 0; i < 16; ++i) {
        int cc = tr + i * 4;
        outT[(size_t)(mat * 512 + n * 64 + cc) * DMODEL + d0 + rr] = f2h(T[rr][cc]);
    }
}

// ---------------------------------------------------------------------------
// Kernel 2: transpose + fp16 convert (W_O).
// ---------------------------------------------------------------------------
__global__ __launch_bounds__(256) void k_transconv_h(const float* __restrict__ in,
                                                     unsigned short* __restrict__ outT,
                                                     int R, int C) {
    __shared__ float T[64][65];
    const int r0 = blockIdx.x * 64, c0 = blockIdx.y * 64;
    const int tr = threadIdx.x >> 6, tc = threadIdx.x & 63;
#pragma unroll
    for (int i = 0; i < 16; ++i)
        T[tr + i * 4][tc] = in[(size_t)(r0 + tr + i * 4) * C + c0 + tc];
    __syncthreads();
    const int rr = tc;
#pragma unroll
    for (int i = 0; i < 16; ++i) {
        int cc = tr + i * 4;
        outT[(size_t)(c0 + cc) * R + r0 + rr] = f2h(T[rr][cc]);
    }
}

// ---------------------------------------------------------------------------
// Kernel 3: elementwise fp32 -> fp16.  (R20's in-GEMM fusion REVERTED:
// reg-staged A broke the gl16 pipeline — MfmaUtil 30.7->16, qkv 70->126 us.)
// ---------------------------------------------------------------------------
__global__ __launch_bounds__(256) void k_convh(const float* __restrict__ in,
                                               unsigned short* __restrict__ out,
                                               int n4) {
    int i = blockIdx.x * 256 + threadIdx.x;
    if (i >= n4) return;
    float4 v = ((const float4*)in)[i];
    ushort4 o;
    o.x = f2h(v.x); o.y = f2h(v.y); o.z = f2h(v.z); o.w = f2h(v.w);
    ((ushort4*)out)[i] = o;
}

// ---------------------------------------------------------------------------
// fp16 2-phase MFMA GEMM staging (R16-verified swizzle: dest linear,
// source inverse-swizzled c^(row&7) on 128B rows -> 0 bank conflicts).
// ---------------------------------------------------------------------------
__device__ __forceinline__ void stage_rows(const unsigned short* __restrict__ src,
                                           unsigned short* lds, int t, int K,
                                           int k0, int nslots4) {
#pragma unroll
    for (int j = 0; j < 8; ++j) {
        if (j >= nslots4) break;
        int slot = j * 256 + t;
        int row = slot >> 3, blk = slot & 7;
        int c = blk ^ (row & 7);
        gl16(src + (size_t)row * K + k0 + c * 8, lds + slot * 8);
    }
}

// ---------------------------------------------------------------------------
// Kernel 4: fp16 GEMM -> QKV.  R16/R18-verified (70 us, MfmaUtil 30.7, 0
// conflicts): tile 128x192, grid 64x8 = 512 blocks, 2 blocks/CU, no tail.
// ---------------------------------------------------------------------------
__global__ __launch_bounds__(256) void k_gemm_qkv(
        const unsigned short* __restrict__ Ag, const unsigned short* __restrict__ Bg,
        unsigned short* __restrict__ qk, unsigned short* __restrict__ vT) {
    __shared__ unsigned short A2[2][128 * 64];
    __shared__ unsigned short B2[2][192 * 64];

    const int t = threadIdx.x;
    const size_t m0 = (size_t)blockIdx.x * 128, n0 = (size_t)blockIdx.y * 192;
    const int w = t >> 6, l = t & 63;
    const int wm = (w >> 1) * 64, wn = (w & 1) * 96;
    const int r = l & 15, q = l >> 4;
    f32x4 acc[4][6] = {};
    const int K = DMODEL;
    const int NT = K / 64;

    stage_rows(Ag + m0 * K, A2[0], t, K, 0, 4);
    stage_rows(Bg + n0 * K, B2[0], t, K, 0, 6);
    asm volatile("s_waitcnt vmcnt(0)" ::: "memory");
    __builtin_amdgcn_s_barrier();
    int cur = 0;
    for (int kt = 0; kt < NT; ++kt) {
        if (kt + 1 < NT) {
            stage_rows(Ag + m0 * K, A2[cur ^ 1], t, K, (kt + 1) * 64, 4);
            stage_rows(Bg + n0 * K, B2[cur ^ 1], t, K, (kt + 1) * 64, 6);
        }
        const unsigned short* Ac = A2[cur];
        const unsigned short* Bc = B2[cur];
        half8 af[4][2], bf[6][2];
#pragma unroll
        for (int i = 0; i < 4; ++i)
#pragma unroll
            for (int ks = 0; ks < 2; ++ks) {
                int ra = wm + i * 16 + r;
                af[i][ks] = *(const half8*)&Ac[ra * 64 + ((((ks << 2) | q) ^ (ra & 7)) << 3)];
            }
#pragma unroll
        for (int j = 0; j < 6; ++j)
#pragma unroll
            for (int ks = 0; ks < 2; ++ks) {
                int rb = wn + j * 16 + r;
                bf[j][ks] = *(const half8*)&Bc[rb * 64 + ((((ks << 2) | q) ^ (rb & 7)) << 3)];
            }
        __builtin_amdgcn_s_setprio(1);
#pragma unroll
        for (int i = 0; i < 4; ++i)
#pragma unroll
            for (int j = 0; j < 6; ++j) {
                acc[i][j] = __builtin_amdgcn_mfma_f32_16x16x32_f16(af[i][0], bf[j][0], acc[i][j], 0, 0, 0);
                acc[i][j] = __builtin_amdgcn_mfma_f32_16x16x32_f16(af[i][1], bf[j][1], acc[i][j], 0, 0, 0);
            }
        __builtin_amdgcn_s_setprio(0);
        asm volatile("s_waitcnt vmcnt(0)" ::: "memory");
        __builtin_amdgcn_s_barrier();
        cur ^= 1;
    }

    // epilogue: per-(i,j) Q/K vs V branch (col boundary 1024 is 16-aligned)
#pragma unroll
    for (int i = 0; i < 4; ++i)
#pragma unroll
        for (int j = 0; j < 6; ++j) {
            int col = (int)n0 + wn + j * 16 + r;
            size_t rowb = m0 + wm + i * 16 + q * 4;
            if (col < 1024) {
#pragma unroll
                for (int e = 0; e < 4; ++e)
                    qk[(rowb + e) * 1024 + col] = f2h(acc[i][j][e]);
            } else {
                int d = col - 1024;
                ushort4 pk;
                pk.x = f2h(acc[i][j][0]); pk.y = f2h(acc[i][j][1]);
                pk.z = f2h(acc[i][j][2]); pk.w = f2h(acc[i][j][3]);
                *(ushort4*)&vT[(size_t)d * MROWS + rowb] = pk;
            }
        }
}

// ---------------------------------------------------------------------------
// Kernel 6: fp16 GEMM 128x128, fp32 C (output projection) — R16-verified.
// ---------------------------------------------------------------------------
__global__ __launch_bounds__(256) void k_gemm_out(
        const unsigned short* __restrict__ Ag, const unsigned short* __restrict__ Bg,
        float* __restrict__ C) {
    __shared__ unsigned short A2[2][128 * 64];
    __shared__ unsigned short B2[2][128 * 64];

    const int t = threadIdx.x;
    const size_t m0 = (size_t)blockIdx.x * 128, n0 = (size_t)blockIdx.y * 128;
    const int w = t >> 6, l = t & 63;
    const int wm = (w >> 1) * 64, wn = (w & 1) * 64;
    const int r = l & 15, q = l >> 4;
    f32x4 acc[4][4] = {};
    const int K = KVDIM;
    const int NT = K / 64;

    stage_rows(Ag + m0 * K, A2[0], t, K, 0, 4);
    stage_rows(Bg + n0 * K, B2[0], t, K, 0, 4);
    asm volatile("s_waitcnt vmcnt(0)" ::: "memory");
    __builtin_amdgcn_s_barrier();
    int cur = 0;
    for (int kt = 0; kt < NT; ++kt) {
        if (kt + 1 < NT) {
            stage_rows(Ag + m0 * K, A2[cur ^ 1], t, K, (kt + 1) * 64, 4);
            stage_rows(Bg + n0 * K, B2[cur ^ 1], t, K, (kt + 1) * 64, 4);
        }
        const unsigned short* Ac = A2[cur];
        const unsigned short* Bc = B2[cur];
        half8 af[4][2], bf[4][2];
#pragma unroll
        for (int i = 0; i < 4; ++i)
#pragma unroll
            for (int ks = 0; ks < 2; ++ks) {
                int ra = wm + i * 16 + r;
                af[i][ks] = *(const half8*)&Ac[ra * 64 + ((((ks << 2) | q) ^ (ra & 7)) << 3)];
                int rb = wn + i * 16 + r;
                bf[i][ks] = *(const half8*)&Bc[rb * 64 + ((((ks << 2) | q) ^ (rb & 7)) << 3)];
            }
        __builtin_amdgcn_s_setprio(1);
#pragma unroll
        for (int i = 0; i < 4; ++i)
#pragma unroll
            for (int j = 0; j < 4; ++j) {
                acc[i][j] = __builtin_amdgcn_mfma_f32_16x16x32_f16(af[i][0], bf[j][0], acc[i][j], 0, 0, 0);
                acc[i][j] = __builtin_amdgcn_mfma_f32_16x16x32_f16(af[i][1], bf[j][1], acc[i][j], 0, 0, 0);
            }
        __builtin_amdgcn_s_setprio(0);
        asm volatile("s_waitcnt vmcnt(0)" ::: "memory");
        __builtin_amdgcn_s_barrier();
        cur ^= 1;
    }

#pragma unroll
    for (int i = 0; i < 4; ++i)
#pragma unroll
        for (int j = 0; j < 4; ++j) {
            int col = (int)n0 + wn + j * 16 + r;
            size_t rowb = m0 + wm + i * 16 + q * 4;
#pragma unroll
            for (int e = 0; e < 4; ++e)
                C[(rowb + e) * DMODEL + col] = acc[i][j][e];
        }
}

// ---------------------------------------------------------------------------
// Kernel 5: fp16 MFMA flash attention — R18-verified (KVBLK=128, QBLK=64,
// pairing p 0..15, 2 blocks/CU, batched-PV with single lgkmcnt drain).
// ---------------------------------------------------------------------------
__global__ __launch_bounds__(256) void k_attn_mfma(
        const unsigned short* __restrict__ qk, const unsigned short* __restrict__ vT,
        unsigned short* __restrict__ zh) {
    __shared__ unsigned short Ks[2][128 * 64];
    __shared__ unsigned short Vs[2][64 * 128];
    __shared__ unsigned short Pt[4 * 128 * 16];   // per-wave 4KB

    const int t  = threadIdx.x;
    const int w  = t >> 6, l = t & 63;
    const int p  = blockIdx.x;        // 0..15 (pair index)
    const int n  = blockIdx.y, b = blockIdx.z;
    const int r  = l & 15, g = l >> 4;
    const int wq0 = w * 16;

#define STAGE_KV(buf, kr0)                                                    \
    _Pragma("unroll") for (int j2 = 0; j2 < 4; ++j2) {                        \
        int s2 = j2 * 256 + t;                                                \
        int rK = s2 >> 3, cK = (s2 & 7) ^ (rK & 7);                           \
        gl16(qk + ((kr0) + rK) * 1024 + 512 + n * 64 + cK * 8,                \
             &Ks[buf][s2 * 8]);                                               \
        int rV = s2 >> 4, cV = (s2 & 15) ^ (rV & 15);                         \
        gl16(vT + (size_t)(n * 64 + rV) * MROWS + (kr0) + cV * 8,             \
             &Vs[buf][s2 * 8]);                                               \
    }

#pragma unroll 1
    for (int seg = 0; seg < 2; ++seg) {
        const int qt = seg ? p : (31 - p);   // heavy tile first
        const int nkt = (qt + 2) >> 1;       // ceil((qt+1)/2) kv-tiles of 128
        const size_t qrow0 = (size_t)(b * SLEN + qt * 64);

        half8 qh[2];
#pragma unroll
        for (int ks = 0; ks < 2; ++ks) {
            size_t off = (qrow0 + wq0 + r) * 1024 + n * 64 + ks * 32 + g * 8;
            qh[ks] = *(const half8*)(qk + off);
#pragma unroll
            for (int e2 = 0; e2 < 8; ++e2) qh[ks][e2] = qh[ks][e2] * (_Float16)0.125f;
        }

        STAGE_KV(0, (size_t)(b * SLEN))
        asm volatile("s_waitcnt vmcnt(0)" ::: "memory");
        __builtin_amdgcn_s_barrier();

        float m_[4], lsum[4];
#pragma unroll
        for (int e = 0; e < 4; ++e) { m_[e] = -3.0e38f; lsum[e] = 0.0f; }
        f32x4 accz[4] = {};

        for (int kt = 0; kt < nkt; ++kt) {
            const int cur = kt & 1;
            if (kt + 1 < nkt) {
                STAGE_KV(cur ^ 1, (size_t)(b * SLEN + (kt + 1) * 128))
            }
            const unsigned short* Ksc = Ks[cur];
            const unsigned short* Vsc = Vs[cur];

            f32x4 s[8] = {};
#pragma unroll
            for (int ct = 0; ct < 8; ++ct)
#pragma unroll
                for (int ks = 0; ks < 2; ++ks) {
                    int row = ct * 16 + r;
                    int off = row * 128 + (((ks * 4 + g) ^ (row & 7)) << 4);
                    half8 kh8 = *(const half8*)((char*)Ksc + off);
                    s[ct] = __builtin_amdgcn_mfma_f32_16x16x32_f16(qh[ks], kh8, s[ct], 0, 0, 0);
                }

            if (kt == nkt - 1) {
#pragma unroll
                for (int ct = 0; ct < 8; ++ct)
#pragma unroll
                    for (int e = 0; e < 4; ++e)
                        if ((kt * 128 + ct * 16 + r) > (qt * 64 + wq0 + g * 4 + e))
                            s[ct][e] = -100000.0f;   // reference IGNORE
            }

            float al[4], nm[4];
#pragma unroll
            for (int e = 0; e < 4; ++e) {
                float pm = fmaxf(fmaxf(fmaxf(s[0][e], s[1][e]), fmaxf(s[2][e], s[3][e])),
                                 fmaxf(fmaxf(s[4][e], s[5][e]), fmaxf(s[6][e], s[7][e])));
                pm = fmaxf(pm, __shfl_xor(pm, 1));
                pm = fmaxf(pm, __shfl_xor(pm, 2));
                pm = fmaxf(pm, __shfl_xor(pm, 4));
                pm = fmaxf(pm, __shfl_xor(pm, 8));
                nm[e] = fmaxf(m_[e], pm);
                al[e] = __expf(m_[e] - nm[e]);
                m_[e] = nm[e];
            }
            {
                int src = (r >> 2) << 4;
                float a0 = __shfl(al[0], src), a1 = __shfl(al[1], src);
                float a2 = __shfl(al[2], src), a3 = __shfl(al[3], src);
                float ax = (r & 1) ? a1 : a0, ay = (r & 1) ? a3 : a2;
                float aq = (r & 2) ? ay : ax;
#pragma unroll
                for (int dt = 0; dt < 4; ++dt) {
                    accz[dt][0] *= aq; accz[dt][1] *= aq;
                    accz[dt][2] *= aq; accz[dt][3] *= aq;
                }
            }

            float ps[4] = {};
#pragma unroll
            for (int ct = 0; ct < 8; ++ct) {
                float p0 = __expf(s[ct][0] - m_[0]);
                float p1 = __expf(s[ct][1] - m_[1]);
                float p2 = __expf(s[ct][2] - m_[2]);
                float p3 = __expf(s[ct][3] - m_[3]);
                ps[0] += p0; ps[1] += p1; ps[2] += p2; ps[3] += p3;
                short4v pk = { (short)f2h(p0), (short)f2h(p1),
                               (short)f2h(p2), (short)f2h(p3) };
                int kv = ct * 16 + r;
                int phys = (kv >> 5) * 32 + (((kv >> 2) & 1) << 4)
                         + (((kv >> 3) & 3) << 2) + (kv & 3);
                *(short4v*)((char*)Pt + w * 4096 + phys * 32 + g * 8) = pk;
            }

#pragma unroll
            for (int e = 0; e < 4; ++e) {
                float rs = ps[e];
                rs += __shfl_xor(rs, 1); rs += __shfl_xor(rs, 2);
                rs += __shfl_xor(rs, 4); rs += __shfl_xor(rs, 8);
                lsum[e] = lsum[e] * al[e] + rs;
            }

            // PV: drain P writes once, issue ALL 8 tr_reads, drain once,
            // then 16 MFMAs.
            asm volatile("s_waitcnt lgkmcnt(0)" ::: "memory");
            __builtin_amdgcn_sched_barrier(0);
            U64S4 tA[4], tB[4];
#pragma unroll
            for (int ks = 0; ks < 4; ++ks) {
                unsigned base = (unsigned)(size_t)((char*)Pt + w * 4096 + ks * 1024) + l * 8;
                asm volatile("ds_read_b64_tr_b16 %0, %1" : "=v"(tA[ks].u) : "v"(base) : "memory");
                asm volatile("ds_read_b64_tr_b16 %0, %1" : "=v"(tB[ks].u) : "v"(base + 512) : "memory");
            }
            asm volatile("s_waitcnt lgkmcnt(0)" ::: "memory");
            __builtin_amdgcn_sched_barrier(0);
#pragma unroll
            for (int ks = 0; ks < 4; ++ks) {
                union { short s[8]; half8 h; } pf;
                pf.s[0] = tA[ks].s[0]; pf.s[1] = tA[ks].s[1];
                pf.s[2] = tA[ks].s[2]; pf.s[3] = tA[ks].s[3];
                pf.s[4] = tB[ks].s[0]; pf.s[5] = tB[ks].s[1];
                pf.s[6] = tB[ks].s[2]; pf.s[7] = tB[ks].s[3];
#pragma unroll
                for (int dt = 0; dt < 4; ++dt) {
                    int d = dt * 16 + r;
                    int off = d * 256 + (((ks * 4 + g) ^ (d & 15)) << 4);
                    half8 vfrag = *(const half8*)((char*)Vsc + off);
                    accz[dt] = __builtin_amdgcn_mfma_f32_16x16x32_f16(vfrag, pf.h, accz[dt], 0, 0, 0);
                }
            }

            asm volatile("s_waitcnt vmcnt(0)" ::: "memory");   // next tile staged
            __builtin_amdgcn_s_barrier();
        }

        int src = (r >> 2) << 4;
        float l0 = __shfl(lsum[0], src), l1 = __shfl(lsum[1], src);
        float l2 = __shfl(lsum[2], src), l3 = __shfl(lsum[3], src);
        float lx = (r & 1) ? l1 : l0, ly = (r & 1) ? l3 : l2;
        float inv = 1.0f / ((r & 2) ? ly : lx);
#pragma unroll
        for (int dt = 0; dt < 4; ++dt) {
            ushort4 h4;
#pragma unroll
            for (int e = 0; e < 4; ++e)
                ((unsigned short*)&h4)[e] = f2h(accz[dt][e] * inv);
            size_t off = (qrow0 + wq0 + r) * 512 + n * 64 + dt * 16 + g * 4;
            *(ushort4*)(zh + off) = h4;
        }
    }
#undef STAGE_KV
}

// ---------------------------------------------------------------------------
// Workspace (bytes, 64 MB used):
//   0   : xh fp16 32M   -> after gemm1: zh fp16 8M (at 0)
//   32M : qk fp16 16M
//   48M : vT fp16 8M
//   56M : wcatT fp16 6M
//   62M : woT fp16 2M
// ---------------------------------------------------------------------------
extern "C" void kernel_launch(void* const* d_in, const int* in_sizes, int n_in,
                              void* d_out, int out_size, void* d_ws, size_t ws_size,
                              hipStream_t stream) {
    const float* x  = (const float*)d_in[0];
    const float* wq = (const float*)d_in[1];
    const float* wk = (const float*)d_in[2];
    const float* wv = (const float*)d_in[3];
    const float* wo = (const float*)d_in[4];
    float* out = (float*)d_out;

    char* w = (char*)d_ws;
    unsigned short* xh  = (unsigned short*)(w);
    unsigned short* zh  = (unsigned short*)(w);
    unsigned short* qk  = (unsigned short*)(w + 33554432);
    unsigned short* vT  = (unsigned short*)(w + 50331648);
    unsigned short* wcatT = (unsigned short*)(w + 58720256);
    unsigned short* woT = (unsigned short*)(w + 65011712);

    k_packT<<<dim3(32, 24), 256, 0, stream>>>(wq, wk, wv, wcatT);
    k_transconv_h<<<dim3(8, 32), 256, 0, stream>>>(wo, woT, KVDIM, DMODEL);
    k_convh<<<dim3(16384), 256, 0, stream>>>(x, xh, MROWS * DMODEL / 4);
    k_gemm_qkv<<<dim3(64, 8), 256, 0, stream>>>(xh, wcatT, qk, vT);
    k_attn_mfma<<<dim3(16, NKV, BATCH), 256, 0, stream>>>(qk, vT, zh);
    k_gemm_out<<<dim3(64, 16), 256, 0, stream>>>(zh, woT, out);
}

// Round 22
// 183.207 us; speedup vs baseline: 1.1706x; 1.0292x over previous
//
#include <hip/hip_runtime.h>

typedef __attribute__((ext_vector_type(8))) _Float16 half8;
typedef __attribute__((ext_vector_type(4))) float f32x4;

#define BATCH  4
#define SLEN   2048
#define DMODEL 2048
#define NKV    8
#define GRP    4
#define DH     64
#define QKV    1536
#define KVDIM  512
#define MROWS  (BATCH * SLEN)   // 8192

// ---- fp16 helper (RNE via hardware cvt) ------------------------------------
__device__ __forceinline__ unsigned short f2h(float f) {
    union { _Float16 h; unsigned short u; } cv;
    cv.h = (_Float16)f;
    return cv.u;
}

// ---- async global->LDS, 16B per lane ---------------------------------------
__device__ __forceinline__ void gl16(const void* g, void* l) {
    __builtin_amdgcn_global_load_lds(
        (const __attribute__((address_space(1))) void*)g,
        (__attribute__((address_space(3))) void*)l, 16, 0, 0);
}

typedef __attribute__((ext_vector_type(4))) short short4v;
union U64S4 { unsigned long long u; short4v s; };

// ---------------------------------------------------------------------------
// Kernel 1 (fused pack + transpose + fp16): wcatT[c][d], c = mat*512+n*64+h.
// ---------------------------------------------------------------------------
__global__ __launch_bounds__(256) void k_packT(const float* __restrict__ wq,
                                               const float* __restrict__ wk,
                                               const float* __restrict__ wv,
                                               unsigned short* __restrict__ outT) {
    __shared__ float T[64][65];
    const int d0 = blockIdx.x * 64;
    const int ct = blockIdx.y;               // 0..23
    const int mat = ct >> 3, n = ct & 7;
    const int tr = threadIdx.x >> 6, tc = threadIdx.x & 63;
#pragma unroll
    for (int i = 0; i < 16; ++i) {
        int row = tr + i * 4;
        float v;
        if (mat == 0) {
            v = 0.0f;
#pragma unroll
            for (int g = 0; g < GRP; ++g)
                v += wq[((size_t)(n * GRP + g) * DMODEL + d0 + row) * DH + tc];
        } else if (mat == 1) {
            v = wk[((size_t)n * DMODEL + d0 + row) * DH + tc];
        } else {
            v = wv[((size_t)n * DMODEL + d0 + row) * DH + tc];
        }
        T[row][tc] = v;
    }
    __syncthreads();
    const int rr = tc;
#pragma unroll
    for (int i = 0; i < 16; ++i) {
        int cc = tr + i * 4;
        outT[(size_t)(mat * 512 + n * 64 + cc) * DMODEL + d0 + rr] = f2h(T[rr][cc]);
    }
}

// ---------------------------------------------------------------------------
// Kernel 2: transpose + fp16 convert (W_O).
// ---------------------------------------------------------------------------
__global__ __launch_bounds__(256) void k_transconv_h(const float* __restrict__ in,
                                                     unsigned short* __restrict__ outT,
                                                     int R, int C) {
    __shared__ float T[64][65];
    const int r0 = blockIdx.x * 64, c0 = blockIdx.y * 64;
    const int tr = threadIdx.x >> 6, tc = threadIdx.x & 63;
#pragma unroll
    for (int i = 0; i < 16; ++i)
        T[tr + i * 4][tc] = in[(size_t)(r0 + tr + i * 4) * C + c0 + tc];
    __syncthreads();
    const int rr = tc;
#pragma unroll
    for (int i = 0; i < 16; ++i) {
        int cc = tr + i * 4;
        outT[(size_t)(c0 + cc) * R + r0 + rr] = f2h(T[rr][cc]);
    }
}

// ---------------------------------------------------------------------------
// Kernel 3: elementwise fp32 -> fp16 (BW-bound, ~6.2 TB/s achieved).
// ---------------------------------------------------------------------------
__global__ __launch_bounds__(256) void k_convh(const float* __restrict__ in,
                                               unsigned short* __restrict__ out,
                                               int n4) {
    int i = blockIdx.x * 256 + threadIdx.x;
    if (i >= n4) return;
    float4 v = ((const float4*)in)[i];
    ushort4 o;
    o.x = f2h(v.x); o.y = f2h(v.y); o.z = f2h(v.z); o.w = f2h(v.w);
    ((ushort4*)out)[i] = o;
}

// ---------------------------------------------------------------------------
// fp16 2-phase MFMA GEMM staging (R16-verified swizzle: dest linear,
// source inverse-swizzled c^(row&7) on 128B rows -> 0 bank conflicts).
// ---------------------------------------------------------------------------
__device__ __forceinline__ void stage_rows(const unsigned short* __restrict__ src,
                                           unsigned short* lds, int t, int K,
                                           int k0, int nslots4) {
#pragma unroll
    for (int j = 0; j < 8; ++j) {
        if (j >= nslots4) break;
        int slot = j * 256 + t;
        int row = slot >> 3, blk = slot & 7;
        int c = blk ^ (row & 7);
        gl16(src + (size_t)row * K + k0 + c * 8, lds + slot * 8);
    }
}

// ---------------------------------------------------------------------------
// Kernel 4: fp16 GEMM -> QKV.  R16/R18-verified (70 us, MfmaUtil 30.7, 0
// conflicts): tile 128x192, grid 64x8 = 512 blocks, 2 blocks/CU, no tail.
// ---------------------------------------------------------------------------
__global__ __launch_bounds__(256) void k_gemm_qkv(
        const unsigned short* __restrict__ Ag, const unsigned short* __restrict__ Bg,
        unsigned short* __restrict__ qk, unsigned short* __restrict__ vT) {
    __shared__ unsigned short A2[2][128 * 64];
    __shared__ unsigned short B2[2][192 * 64];

    const int t = threadIdx.x;
    const size_t m0 = (size_t)blockIdx.x * 128, n0 = (size_t)blockIdx.y * 192;
    const int w = t >> 6, l = t & 63;
    const int wm = (w >> 1) * 64, wn = (w & 1) * 96;
    const int r = l & 15, q = l >> 4;
    f32x4 acc[4][6] = {};
    const int K = DMODEL;
    const int NT = K / 64;

    stage_rows(Ag + m0 * K, A2[0], t, K, 0, 4);
    stage_rows(Bg + n0 * K, B2[0], t, K, 0, 6);
    asm volatile("s_waitcnt vmcnt(0)" ::: "memory");
    __builtin_amdgcn_s_barrier();
    int cur = 0;
    for (int kt = 0; kt < NT; ++kt) {
        if (kt + 1 < NT) {
            stage_rows(Ag + m0 * K, A2[cur ^ 1], t, K, (kt + 1) * 64, 4);
            stage_rows(Bg + n0 * K, B2[cur ^ 1], t, K, (kt + 1) * 64, 6);
        }
        const unsigned short* Ac = A2[cur];
        const unsigned short* Bc = B2[cur];
        half8 af[4][2], bf[6][2];
#pragma unroll
        for (int i = 0; i < 4; ++i)
#pragma unroll
            for (int ks = 0; ks < 2; ++ks) {
                int ra = wm + i * 16 + r;
                af[i][ks] = *(const half8*)&Ac[ra * 64 + ((((ks << 2) | q) ^ (ra & 7)) << 3)];
            }
#pragma unroll
        for (int j = 0; j < 6; ++j)
#pragma unroll
            for (int ks = 0; ks < 2; ++ks) {
                int rb = wn + j * 16 + r;
                bf[j][ks] = *(const half8*)&Bc[rb * 64 + ((((ks << 2) | q) ^ (rb & 7)) << 3)];
            }
        __builtin_amdgcn_s_setprio(1);
#pragma unroll
        for (int i = 0; i < 4; ++i)
#pragma unroll
            for (int j = 0; j < 6; ++j) {
                acc[i][j] = __builtin_amdgcn_mfma_f32_16x16x32_f16(af[i][0], bf[j][0], acc[i][j], 0, 0, 0);
                acc[i][j] = __builtin_amdgcn_mfma_f32_16x16x32_f16(af[i][1], bf[j][1], acc[i][j], 0, 0, 0);
            }
        __builtin_amdgcn_s_setprio(0);
        asm volatile("s_waitcnt vmcnt(0)" ::: "memory");
        __builtin_amdgcn_s_barrier();
        cur ^= 1;
    }

    // epilogue: per-(i,j) Q/K vs V branch (col boundary 1024 is 16-aligned)
#pragma unroll
    for (int i = 0; i < 4; ++i)
#pragma unroll
        for (int j = 0; j < 6; ++j) {
            int col = (int)n0 + wn + j * 16 + r;
            size_t rowb = m0 + wm + i * 16 + q * 4;
            if (col < 1024) {
#pragma unroll
                for (int e = 0; e < 4; ++e)
                    qk[(rowb + e) * 1024 + col] = f2h(acc[i][j][e]);
            } else {
                int d = col - 1024;
                ushort4 pk;
                pk.x = f2h(acc[i][j][0]); pk.y = f2h(acc[i][j][1]);
                pk.z = f2h(acc[i][j][2]); pk.w = f2h(acc[i][j][3]);
                *(ushort4*)&vT[(size_t)d * MROWS + rowb] = pk;
            }
        }
}

// ---------------------------------------------------------------------------
// Kernel 6: fp16 GEMM 128x128, fp32 C (output projection) — R16-verified.
// ---------------------------------------------------------------------------
__global__ __launch_bounds__(256) void k_gemm_out(
        const unsigned short* __restrict__ Ag, const unsigned short* __restrict__ Bg,
        float* __restrict__ C) {
    __shared__ unsigned short A2[2][128 * 64];
    __shared__ unsigned short B2[2][128 * 64];

    const int t = threadIdx.x;
    const size_t m0 = (size_t)blockIdx.x * 128, n0 = (size_t)blockIdx.y * 128;
    const int w = t >> 6, l = t & 63;
    const int wm = (w >> 1) * 64, wn = (w & 1) * 64;
    const int r = l & 15, q = l >> 4;
    f32x4 acc[4][4] = {};
    const int K = KVDIM;
    const int NT = K / 64;

    stage_rows(Ag + m0 * K, A2[0], t, K, 0, 4);
    stage_rows(Bg + n0 * K, B2[0], t, K, 0, 4);
    asm volatile("s_waitcnt vmcnt(0)" ::: "memory");
    __builtin_amdgcn_s_barrier();
    int cur = 0;
    for (int kt = 0; kt < NT; ++kt) {
        if (kt + 1 < NT) {
            stage_rows(Ag + m0 * K, A2[cur ^ 1], t, K, (kt + 1) * 64, 4);
            stage_rows(Bg + n0 * K, B2[cur ^ 1], t, K, (kt + 1) * 64, 4);
        }
        const unsigned short* Ac = A2[cur];
        const unsigned short* Bc = B2[cur];
        half8 af[4][2], bf[4][2];
#pragma unroll
        for (int i = 0; i < 4; ++i)
#pragma unroll
            for (int ks = 0; ks < 2; ++ks) {
                int ra = wm + i * 16 + r;
                af[i][ks] = *(const half8*)&Ac[ra * 64 + ((((ks << 2) | q) ^ (ra & 7)) << 3)];
                int rb = wn + i * 16 + r;
                bf[i][ks] = *(const half8*)&Bc[rb * 64 + ((((ks << 2) | q) ^ (rb & 7)) << 3)];
            }
        __builtin_amdgcn_s_setprio(1);
#pragma unroll
        for (int i = 0; i < 4; ++i)
#pragma unroll
            for (int j = 0; j < 4; ++j) {
                acc[i][j] = __builtin_amdgcn_mfma_f32_16x16x32_f16(af[i][0], bf[j][0], acc[i][j], 0, 0, 0);
                acc[i][j] = __builtin_amdgcn_mfma_f32_16x16x32_f16(af[i][1], bf[j][1], acc[i][j], 0, 0, 0);
            }
        __builtin_amdgcn_s_setprio(0);
        asm volatile("s_waitcnt vmcnt(0)" ::: "memory");
        __builtin_amdgcn_s_barrier();
        cur ^= 1;
    }

#pragma unroll
    for (int i = 0; i < 4; ++i)
#pragma unroll
        for (int j = 0; j < 4; ++j) {
            int col = (int)n0 + wn + j * 16 + r;
            size_t rowb = m0 + wm + i * 16 + q * 4;
#pragma unroll
            for (int e = 0; e < 4; ++e)
                C[(rowb + e) * DMODEL + col] = acc[i][j][e];
        }
}

// ---------------------------------------------------------------------------
// Kernel 5: fp16 MFMA flash attention (R18 base).  R22 change: LAZY LSUM —
// per-tile sum shuffle-chain deleted.  Since alpha is row-uniform across
// the 16 r-lanes, each lane carries a private partial lsum_r = lsum_r*al +
// ps_r; the cross-lane reduce happens ONCE after the kv loop.  Linearity
// makes this exact up to fp add order (positive sum, tolerance-safe).
// ---------------------------------------------------------------------------
__global__ __launch_bounds__(256) void k_attn_mfma(
        const unsigned short* __restrict__ qk, const unsigned short* __restrict__ vT,
        unsigned short* __restrict__ zh) {
    __shared__ unsigned short Ks[2][128 * 64];
    __shared__ unsigned short Vs[2][64 * 128];
    __shared__ unsigned short Pt[4 * 128 * 16];   // per-wave 4KB

    const int t  = threadIdx.x;
    const int w  = t >> 6, l = t & 63;
    const int p  = blockIdx.x;        // 0..15 (pair index)
    const int n  = blockIdx.y, b = blockIdx.z;
    const int r  = l & 15, g = l >> 4;
    const int wq0 = w * 16;

#define STAGE_KV(buf, kr0)                                                    \
    _Pragma("unroll") for (int j2 = 0; j2 < 4; ++j2) {                        \
        int s2 = j2 * 256 + t;                                                \
        int rK = s2 >> 3, cK = (s2 & 7) ^ (rK & 7);                           \
        gl16(qk + ((kr0) + rK) * 1024 + 512 + n * 64 + cK * 8,                \
             &Ks[buf][s2 * 8]);                                               \
        int rV = s2 >> 4, cV = (s2 & 15) ^ (rV & 15);                         \
        gl16(vT + (size_t)(n * 64 + rV) * MROWS + (kr0) + cV * 8,             \
             &Vs[buf][s2 * 8]);                                               \
    }

#pragma unroll 1
    for (int seg = 0; seg < 2; ++seg) {
        const int qt = seg ? p : (31 - p);   // heavy tile first
        const int nkt = (qt + 2) >> 1;       // ceil((qt+1)/2) kv-tiles of 128
        const size_t qrow0 = (size_t)(b * SLEN + qt * 64);

        half8 qh[2];
#pragma unroll
        for (int ks = 0; ks < 2; ++ks) {
            size_t off = (qrow0 + wq0 + r) * 1024 + n * 64 + ks * 32 + g * 8;
            qh[ks] = *(const half8*)(qk + off);
#pragma unroll
            for (int e2 = 0; e2 < 8; ++e2) qh[ks][e2] = qh[ks][e2] * (_Float16)0.125f;
        }

        STAGE_KV(0, (size_t)(b * SLEN))
        asm volatile("s_waitcnt vmcnt(0)" ::: "memory");
        __builtin_amdgcn_s_barrier();

        float m_[4], lsum[4];   // lsum = PER-LANE partial (lazy reduction)
#pragma unroll
        for (int e = 0; e < 4; ++e) { m_[e] = -3.0e38f; lsum[e] = 0.0f; }
        f32x4 accz[4] = {};

        for (int kt = 0; kt < nkt; ++kt) {
            const int cur = kt & 1;
            if (kt + 1 < nkt) {
                STAGE_KV(cur ^ 1, (size_t)(b * SLEN + (kt + 1) * 128))
            }
            const unsigned short* Ksc = Ks[cur];
            const unsigned short* Vsc = Vs[cur];

            f32x4 s[8] = {};
#pragma unroll
            for (int ct = 0; ct < 8; ++ct)
#pragma unroll
                for (int ks = 0; ks < 2; ++ks) {
                    int row = ct * 16 + r;
                    int off = row * 128 + (((ks * 4 + g) ^ (row & 7)) << 4);
                    half8 kh8 = *(const half8*)((char*)Ksc + off);
                    s[ct] = __builtin_amdgcn_mfma_f32_16x16x32_f16(qh[ks], kh8, s[ct], 0, 0, 0);
                }

            if (kt == nkt - 1) {
#pragma unroll
                for (int ct = 0; ct < 8; ++ct)
#pragma unroll
                    for (int e = 0; e < 4; ++e)
                        if ((kt * 128 + ct * 16 + r) > (qt * 64 + wq0 + g * 4 + e))
                            s[ct][e] = -100000.0f;   // reference IGNORE
            }

            float al[4];
#pragma unroll
            for (int e = 0; e < 4; ++e) {
                float pm = fmaxf(fmaxf(fmaxf(s[0][e], s[1][e]), fmaxf(s[2][e], s[3][e])),
                                 fmaxf(fmaxf(s[4][e], s[5][e]), fmaxf(s[6][e], s[7][e])));
                pm = fmaxf(pm, __shfl_xor(pm, 1));
                pm = fmaxf(pm, __shfl_xor(pm, 2));
                pm = fmaxf(pm, __shfl_xor(pm, 4));
                pm = fmaxf(pm, __shfl_xor(pm, 8));
                float nm = fmaxf(m_[e], pm);
                al[e] = __expf(m_[e] - nm);
                m_[e] = nm;
            }
            {
                int src = (r >> 2) << 4;
                float a0 = __shfl(al[0], src), a1 = __shfl(al[1], src);
                float a2 = __shfl(al[2], src), a3 = __shfl(al[3], src);
                float ax = (r & 1) ? a1 : a0, ay = (r & 1) ? a3 : a2;
                float aq = (r & 2) ? ay : ax;
#pragma unroll
                for (int dt = 0; dt < 4; ++dt) {
                    accz[dt][0] *= aq; accz[dt][1] *= aq;
                    accz[dt][2] *= aq; accz[dt][3] *= aq;
                }
            }

            float ps[4] = {};
#pragma unroll
            for (int ct = 0; ct < 8; ++ct) {
                float p0 = __expf(s[ct][0] - m_[0]);
                float p1 = __expf(s[ct][1] - m_[1]);
                float p2 = __expf(s[ct][2] - m_[2]);
                float p3 = __expf(s[ct][3] - m_[3]);
                ps[0] += p0; ps[1] += p1; ps[2] += p2; ps[3] += p3;
                short4v pk = { (short)f2h(p0), (short)f2h(p1),
                               (short)f2h(p2), (short)f2h(p3) };
                int kv = ct * 16 + r;
                int phys = (kv >> 5) * 32 + (((kv >> 2) & 1) << 4)
                         + (((kv >> 3) & 3) << 2) + (kv & 3);
                *(short4v*)((char*)Pt + w * 4096 + phys * 32 + g * 8) = pk;
            }

            // LAZY: per-lane partial update only (no shuffle chain here)
#pragma unroll
            for (int e = 0; e < 4; ++e)
                lsum[e] = lsum[e] * al[e] + ps[e];

            // PV: drain P writes once, issue ALL 8 tr_reads, drain once,
            // then 16 MFMAs.
            asm volatile("s_waitcnt lgkmcnt(0)" ::: "memory");
            __builtin_amdgcn_sched_barrier(0);
            U64S4 tA[4], tB[4];
#pragma unroll
            for (int ks = 0; ks < 4; ++ks) {
                unsigned base = (unsigned)(size_t)((char*)Pt + w * 4096 + ks * 1024) + l * 8;
                asm volatile("ds_read_b64_tr_b16 %0, %1" : "=v"(tA[ks].u) : "v"(base) : "memory");
                asm volatile("ds_read_b64_tr_b16 %0, %1" : "=v"(tB[ks].u) : "v"(base + 512) : "memory");
            }
            asm volatile("s_waitcnt lgkmcnt(0)" ::: "memory");
            __builtin_amdgcn_sched_barrier(0);
#pragma unroll
            for (int ks = 0; ks < 4; ++ks) {
                union { short s[8]; half8 h; } pf;
                pf.s[0] = tA[ks].s[0]; pf.s[1] = tA[ks].s[1];
                pf.s[2] = tA[ks].s[2]; pf.s[3] = tA[ks].s[3];
                pf.s[4] = tB[ks].s[0]; pf.s[5] = tB[ks].s[1];
                pf.s[6] = tB[ks].s[2]; pf.s[7] = tB[ks].s[3];
#pragma unroll
                for (int dt = 0; dt < 4; ++dt) {
                    int d = dt * 16 + r;
                    int off = d * 256 + (((ks * 4 + g) ^ (d & 15)) << 4);
                    half8 vfrag = *(const half8*)((char*)Vsc + off);
                    accz[dt] = __builtin_amdgcn_mfma_f32_16x16x32_f16(vfrag, pf.h, accz[dt], 0, 0, 0);
                }
            }

            asm volatile("s_waitcnt vmcnt(0)" ::: "memory");   // next tile staged
            __builtin_amdgcn_s_barrier();
        }

        // final cross-lane lsum reduce (moved out of the kv loop)
#pragma unroll
        for (int e = 0; e < 4; ++e) {
            float rs = lsum[e];
            rs += __shfl_xor(rs, 1); rs += __shfl_xor(rs, 2);
            rs += __shfl_xor(rs, 4); rs += __shfl_xor(rs, 8);
            lsum[e] = rs;
        }

        int src = (r >> 2) << 4;
        float l0 = __shfl(lsum[0], src), l1 = __shfl(lsum[1], src);
        float l2 = __shfl(lsum[2], src), l3 = __shfl(lsum[3], src);
        float lx = (r & 1) ? l1 : l0, ly = (r & 1) ? l3 : l2;
        float inv = 1.0f / ((r & 2) ? ly : lx);
#pragma unroll
        for (int dt = 0; dt < 4; ++dt) {
            ushort4 h4;
#pragma unroll
            for (int e = 0; e < 4; ++e)
                ((unsigned short*)&h4)[e] = f2h(accz[dt][e] * inv);
            size_t off = (qrow0 + wq0 + r) * 512 + n * 64 + dt * 16 + g * 4;
            *(ushort4*)(zh + off) = h4;
        }
    }
#undef STAGE_KV
}

// ---------------------------------------------------------------------------
// Workspace (bytes, 64 MB used):
//   0   : xh fp16 32M   -> after gemm1: zh fp16 8M (at 0)
//   32M : qk fp16 16M
//   48M : vT fp16 8M
//   56M : wcatT fp16 6M
//   62M : woT fp16 2M
// ---------------------------------------------------------------------------
extern "C" void kernel_launch(void* const* d_in, const int* in_sizes, int n_in,
                              void* d_out, int out_size, void* d_ws, size_t ws_size,
                              hipStream_t stream) {
    const float* x  = (const float*)d_in[0];
    const float* wq = (const float*)d_in[1];
    const float* wk = (const float*)d_in[2];
    const float* wv = (const float*)d_in[3];
    const float* wo = (const float*)d_in[4];
    float* out = (float*)d_out;

    char* w = (char*)d_ws;
    unsigned short* xh  = (unsigned short*)(w);
    unsigned short* zh  = (unsigned short*)(w);
    unsigned short* qk  = (unsigned short*)(w + 33554432);
    unsigned short* vT  = (unsigned short*)(w + 50331648);
    unsigned short* wcatT = (unsigned short*)(w + 58720256);
    unsigned short* woT = (unsigned short*)(w + 65011712);

    k_packT<<<dim3(32, 24), 256, 0, stream>>>(wq, wk, wv, wcatT);
    k_transconv_h<<<dim3(8, 32), 256, 0, stream>>>(wo, woT, KVDIM, DMODEL);
    k_convh<<<dim3(16384), 256, 0, stream>>>(x, xh, MROWS * DMODEL / 4);
    k_gemm_qkv<<<dim3(64, 8), 256, 0, stream>>>(xh, wcatT, qk, vT);
    k_attn_mfma<<<dim3(16, NKV, BATCH), 256, 0, stream>>>(qk, vT, zh);
    k_gemm_out<<<dim3(64, 16), 256, 0, stream>>>(zh, woT, out);
}

// Round 23
// 180.664 us; speedup vs baseline: 1.1870x; 1.0141x over previous
//
#include <hip/hip_runtime.h>

typedef __attribute__((ext_vector_type(8))) _Float16 half8;
typedef __attribute__((ext_vector_type(4))) float f32x4;

#define BATCH  4
#define SLEN   2048
#define DMODEL 2048
#define NKV    8
#define GRP    4
#define DH     64
#define QKV    1536
#define KVDIM  512
#define MROWS  (BATCH * SLEN)   // 8192

// ---- fp16 helper (RNE via hardware cvt) ------------------------------------
__device__ __forceinline__ unsigned short f2h(float f) {
    union { _Float16 h; unsigned short u; } cv;
    cv.h = (_Float16)f;
    return cv.u;
}

// ---- async global->LDS, 16B per lane ---------------------------------------
__device__ __forceinline__ void gl16(const void* g, void* l) {
    __builtin_amdgcn_global_load_lds(
        (const __attribute__((address_space(1))) void*)g,
        (__attribute__((address_space(3))) void*)l, 16, 0, 0);
}

typedef __attribute__((ext_vector_type(4))) short short4v;
union U64S4 { unsigned long long u; short4v s; };

// ---------------------------------------------------------------------------
// Kernel 1 (fused prep, one launch): three independent jobs branch on
// blockIdx.x range (wave-uniform):
//   [0, 16384)       : x fp32 -> xh fp16 (elementwise, BW-bound)
//   [16384, 17152)   : packT  — wcatT[c][d] = f2h(sum_g WQ | WK | WV)^T
//   [17152, 17408)   : transconv — woT fp16 [2048][512] from wo fp32
// Merging overlaps the small jobs' latency with convh's BW stream and
// removes two launch boundaries.
// ---------------------------------------------------------------------------
__global__ __launch_bounds__(256) void k_prep(const float* __restrict__ x,
                                              const float* __restrict__ wq,
                                              const float* __restrict__ wk,
                                              const float* __restrict__ wv,
                                              const float* __restrict__ wo,
                                              unsigned short* __restrict__ xh,
                                              unsigned short* __restrict__ wcatT,
                                              unsigned short* __restrict__ woT) {
    const int bx = blockIdx.x;
    if (bx < 16384) {
        // ---- convh: 16384 blocks x 256 thr x 4 floats = 16M float4
        int i = bx * 256 + threadIdx.x;
        float4 v = ((const float4*)x)[i];
        ushort4 o;
        o.x = f2h(v.x); o.y = f2h(v.y); o.z = f2h(v.z); o.w = f2h(v.w);
        ((ushort4*)xh)[i] = o;
    } else if (bx < 17152) {
        // ---- packT: 768 blocks = 32 d-tiles x 24 (mat,n)
        __shared__ float T[64][65];
        const int bp = bx - 16384;
        const int d0 = (bp & 31) * 64;
        const int ct = bp >> 5;              // 0..23
        const int mat = ct >> 3, n = ct & 7;
        const int tr = threadIdx.x >> 6, tc = threadIdx.x & 63;
#pragma unroll
        for (int i = 0; i < 16; ++i) {
            int row = tr + i * 4;
            float v;
            if (mat == 0) {
                v = 0.0f;
#pragma unroll
                for (int g = 0; g < GRP; ++g)
                    v += wq[((size_t)(n * GRP + g) * DMODEL + d0 + row) * DH + tc];
            } else if (mat == 1) {
                v = wk[((size_t)n * DMODEL + d0 + row) * DH + tc];
            } else {
                v = wv[((size_t)n * DMODEL + d0 + row) * DH + tc];
            }
            T[row][tc] = v;
        }
        __syncthreads();
        const int rr = tc;
#pragma unroll
        for (int i = 0; i < 16; ++i) {
            int cc = tr + i * 4;
            wcatT[(size_t)(mat * 512 + n * 64 + cc) * DMODEL + d0 + rr] = f2h(T[rr][cc]);
        }
    } else {
        // ---- transconv W_O: 256 blocks = 8 r-tiles x 32 c-tiles
        __shared__ float T[64][65];
        const int bp = bx - 17152;
        const int r0 = (bp & 7) * 64, c0 = (bp >> 3) * 64;
        const int tr = threadIdx.x >> 6, tc = threadIdx.x & 63;
#pragma unroll
        for (int i = 0; i < 16; ++i)
            T[tr + i * 4][tc] = wo[(size_t)(r0 + tr + i * 4) * DMODEL + c0 + tc];
        __syncthreads();
        const int rr = tc;
#pragma unroll
        for (int i = 0; i < 16; ++i) {
            int cc = tr + i * 4;
            woT[(size_t)(c0 + cc) * KVDIM + r0 + rr] = f2h(T[rr][cc]);
        }
    }
}

// ---------------------------------------------------------------------------
// fp16 2-phase MFMA GEMM staging (R16-verified swizzle: dest linear,
// source inverse-swizzled c^(row&7) on 128B rows -> 0 bank conflicts).
// ---------------------------------------------------------------------------
__device__ __forceinline__ void stage_rows(const unsigned short* __restrict__ src,
                                           unsigned short* lds, int t, int K,
                                           int k0, int nslots4) {
#pragma unroll
    for (int j = 0; j < 8; ++j) {
        if (j >= nslots4) break;
        int slot = j * 256 + t;
        int row = slot >> 3, blk = slot & 7;
        int c = blk ^ (row & 7);
        gl16(src + (size_t)row * K + k0 + c * 8, lds + slot * 8);
    }
}

// ---------------------------------------------------------------------------
// Kernel 4: fp16 GEMM -> QKV.  R16/R18-verified (70 us, MfmaUtil 30.7, 0
// conflicts): tile 128x192, grid 64x8 = 512 blocks, 2 blocks/CU, no tail.
// ---------------------------------------------------------------------------
__global__ __launch_bounds__(256) void k_gemm_qkv(
        const unsigned short* __restrict__ Ag, const unsigned short* __restrict__ Bg,
        unsigned short* __restrict__ qk, unsigned short* __restrict__ vT) {
    __shared__ unsigned short A2[2][128 * 64];
    __shared__ unsigned short B2[2][192 * 64];

    const int t = threadIdx.x;
    const size_t m0 = (size_t)blockIdx.x * 128, n0 = (size_t)blockIdx.y * 192;
    const int w = t >> 6, l = t & 63;
    const int wm = (w >> 1) * 64, wn = (w & 1) * 96;
    const int r = l & 15, q = l >> 4;
    f32x4 acc[4][6] = {};
    const int K = DMODEL;
    const int NT = K / 64;

    stage_rows(Ag + m0 * K, A2[0], t, K, 0, 4);
    stage_rows(Bg + n0 * K, B2[0], t, K, 0, 6);
    asm volatile("s_waitcnt vmcnt(0)" ::: "memory");
    __builtin_amdgcn_s_barrier();
    int cur = 0;
    for (int kt = 0; kt < NT; ++kt) {
        if (kt + 1 < NT) {
            stage_rows(Ag + m0 * K, A2[cur ^ 1], t, K, (kt + 1) * 64, 4);
            stage_rows(Bg + n0 * K, B2[cur ^ 1], t, K, (kt + 1) * 64, 6);
        }
        const unsigned short* Ac = A2[cur];
        const unsigned short* Bc = B2[cur];
        half8 af[4][2], bf[6][2];
#pragma unroll
        for (int i = 0; i < 4; ++i)
#pragma unroll
            for (int ks = 0; ks < 2; ++ks) {
                int ra = wm + i * 16 + r;
                af[i][ks] = *(const half8*)&Ac[ra * 64 + ((((ks << 2) | q) ^ (ra & 7)) << 3)];
            }
#pragma unroll
        for (int j = 0; j < 6; ++j)
#pragma unroll
            for (int ks = 0; ks < 2; ++ks) {
                int rb = wn + j * 16 + r;
                bf[j][ks] = *(const half8*)&Bc[rb * 64 + ((((ks << 2) | q) ^ (rb & 7)) << 3)];
            }
        __builtin_amdgcn_s_setprio(1);
#pragma unroll
        for (int i = 0; i < 4; ++i)
#pragma unroll
            for (int j = 0; j < 6; ++j) {
                acc[i][j] = __builtin_amdgcn_mfma_f32_16x16x32_f16(af[i][0], bf[j][0], acc[i][j], 0, 0, 0);
                acc[i][j] = __builtin_amdgcn_mfma_f32_16x16x32_f16(af[i][1], bf[j][1], acc[i][j], 0, 0, 0);
            }
        __builtin_amdgcn_s_setprio(0);
        asm volatile("s_waitcnt vmcnt(0)" ::: "memory");
        __builtin_amdgcn_s_barrier();
        cur ^= 1;
    }

    // epilogue: per-(i,j) Q/K vs V branch (col boundary 1024 is 16-aligned)
#pragma unroll
    for (int i = 0; i < 4; ++i)
#pragma unroll
        for (int j = 0; j < 6; ++j) {
            int col = (int)n0 + wn + j * 16 + r;
            size_t rowb = m0 + wm + i * 16 + q * 4;
            if (col < 1024) {
#pragma unroll
                for (int e = 0; e < 4; ++e)
                    qk[(rowb + e) * 1024 + col] = f2h(acc[i][j][e]);
            } else {
                int d = col - 1024;
                ushort4 pk;
                pk.x = f2h(acc[i][j][0]); pk.y = f2h(acc[i][j][1]);
                pk.z = f2h(acc[i][j][2]); pk.w = f2h(acc[i][j][3]);
                *(ushort4*)&vT[(size_t)d * MROWS + rowb] = pk;
            }
        }
}

// ---------------------------------------------------------------------------
// Kernel 6: fp16 GEMM 128x128, fp32 C (output projection) — R16-verified.
// ---------------------------------------------------------------------------
__global__ __launch_bounds__(256) void k_gemm_out(
        const unsigned short* __restrict__ Ag, const unsigned short* __restrict__ Bg,
        float* __restrict__ C) {
    __shared__ unsigned short A2[2][128 * 64];
    __shared__ unsigned short B2[2][128 * 64];

    const int t = threadIdx.x;
    const size_t m0 = (size_t)blockIdx.x * 128, n0 = (size_t)blockIdx.y * 128;
    const int w = t >> 6, l = t & 63;
    const int wm = (w >> 1) * 64, wn = (w & 1) * 64;
    const int r = l & 15, q = l >> 4;
    f32x4 acc[4][4] = {};
    const int K = KVDIM;
    const int NT = K / 64;

    stage_rows(Ag + m0 * K, A2[0], t, K, 0, 4);
    stage_rows(Bg + n0 * K, B2[0], t, K, 0, 4);
    asm volatile("s_waitcnt vmcnt(0)" ::: "memory");
    __builtin_amdgcn_s_barrier();
    int cur = 0;
    for (int kt = 0; kt < NT; ++kt) {
        if (kt + 1 < NT) {
            stage_rows(Ag + m0 * K, A2[cur ^ 1], t, K, (kt + 1) * 64, 4);
            stage_rows(Bg + n0 * K, B2[cur ^ 1], t, K, (kt + 1) * 64, 4);
        }
        const unsigned short* Ac = A2[cur];
        const unsigned short* Bc = B2[cur];
        half8 af[4][2], bf[4][2];
#pragma unroll
        for (int i = 0; i < 4; ++i)
#pragma unroll
            for (int ks = 0; ks < 2; ++ks) {
                int ra = wm + i * 16 + r;
                af[i][ks] = *(const half8*)&Ac[ra * 64 + ((((ks << 2) | q) ^ (ra & 7)) << 3)];
                int rb = wn + i * 16 + r;
                bf[i][ks] = *(const half8*)&Bc[rb * 64 + ((((ks << 2) | q) ^ (rb & 7)) << 3)];
            }
        __builtin_amdgcn_s_setprio(1);
#pragma unroll
        for (int i = 0; i < 4; ++i)
#pragma unroll
            for (int j = 0; j < 4; ++j) {
                acc[i][j] = __builtin_amdgcn_mfma_f32_16x16x32_f16(af[i][0], bf[j][0], acc[i][j], 0, 0, 0);
                acc[i][j] = __builtin_amdgcn_mfma_f32_16x16x32_f16(af[i][1], bf[j][1], acc[i][j], 0, 0, 0);
            }
        __builtin_amdgcn_s_setprio(0);
        asm volatile("s_waitcnt vmcnt(0)" ::: "memory");
        __builtin_amdgcn_s_barrier();
        cur ^= 1;
    }

#pragma unroll
    for (int i = 0; i < 4; ++i)
#pragma unroll
        for (int j = 0; j < 4; ++j) {
            int col = (int)n0 + wn + j * 16 + r;
            size_t rowb = m0 + wm + i * 16 + q * 4;
#pragma unroll
            for (int e = 0; e < 4; ++e)
                C[(rowb + e) * DMODEL + col] = acc[i][j][e];
        }
}

// ---------------------------------------------------------------------------
// Kernel 5: fp16 MFMA flash attention (R18 base + R22 lazy lsum, verified
// 183.2 us total).
// ---------------------------------------------------------------------------
__global__ __launch_bounds__(256) void k_attn_mfma(
        const unsigned short* __restrict__ qk, const unsigned short* __restrict__ vT,
        unsigned short* __restrict__ zh) {
    __shared__ unsigned short Ks[2][128 * 64];
    __shared__ unsigned short Vs[2][64 * 128];
    __shared__ unsigned short Pt[4 * 128 * 16];   // per-wave 4KB

    const int t  = threadIdx.x;
    const int w  = t >> 6, l = t & 63;
    const int p  = blockIdx.x;        // 0..15 (pair index)
    const int n  = blockIdx.y, b = blockIdx.z;
    const int r  = l & 15, g = l >> 4;
    const int wq0 = w * 16;

#define STAGE_KV(buf, kr0)                                                    \
    _Pragma("unroll") for (int j2 = 0; j2 < 4; ++j2) {                        \
        int s2 = j2 * 256 + t;                                                \
        int rK = s2 >> 3, cK = (s2 & 7) ^ (rK & 7);                           \
        gl16(qk + ((kr0) + rK) * 1024 + 512 + n * 64 + cK * 8,                \
             &Ks[buf][s2 * 8]);                                               \
        int rV = s2 >> 4, cV = (s2 & 15) ^ (rV & 15);                         \
        gl16(vT + (size_t)(n * 64 + rV) * MROWS + (kr0) + cV * 8,             \
             &Vs[buf][s2 * 8]);                                               \
    }

#pragma unroll 1
    for (int seg = 0; seg < 2; ++seg) {
        const int qt = seg ? p : (31 - p);   // heavy tile first
        const int nkt = (qt + 2) >> 1;       // ceil((qt+1)/2) kv-tiles of 128
        const size_t qrow0 = (size_t)(b * SLEN + qt * 64);

        half8 qh[2];
#pragma unroll
        for (int ks = 0; ks < 2; ++ks) {
            size_t off = (qrow0 + wq0 + r) * 1024 + n * 64 + ks * 32 + g * 8;
            qh[ks] = *(const half8*)(qk + off);
#pragma unroll
            for (int e2 = 0; e2 < 8; ++e2) qh[ks][e2] = qh[ks][e2] * (_Float16)0.125f;
        }

        STAGE_KV(0, (size_t)(b * SLEN))
        asm volatile("s_waitcnt vmcnt(0)" ::: "memory");
        __builtin_amdgcn_s_barrier();

        float m_[4], lsum[4];   // lsum = PER-LANE partial (lazy reduction)
#pragma unroll
        for (int e = 0; e < 4; ++e) { m_[e] = -3.0e38f; lsum[e] = 0.0f; }
        f32x4 accz[4] = {};

        for (int kt = 0; kt < nkt; ++kt) {
            const int cur = kt & 1;
            if (kt + 1 < nkt) {
                STAGE_KV(cur ^ 1, (size_t)(b * SLEN + (kt + 1) * 128))
            }
            const unsigned short* Ksc = Ks[cur];
            const unsigned short* Vsc = Vs[cur];

            f32x4 s[8] = {};
#pragma unroll
            for (int ct = 0; ct < 8; ++ct)
#pragma unroll
                for (int ks = 0; ks < 2; ++ks) {
                    int row = ct * 16 + r;
                    int off = row * 128 + (((ks * 4 + g) ^ (row & 7)) << 4);
                    half8 kh8 = *(const half8*)((char*)Ksc + off);
                    s[ct] = __builtin_amdgcn_mfma_f32_16x16x32_f16(qh[ks], kh8, s[ct], 0, 0, 0);
                }

            if (kt == nkt - 1) {
#pragma unroll
                for (int ct = 0; ct < 8; ++ct)
#pragma unroll
                    for (int e = 0; e < 4; ++e)
                        if ((kt * 128 + ct * 16 + r) > (qt * 64 + wq0 + g * 4 + e))
                            s[ct][e] = -100000.0f;   // reference IGNORE
            }

            float al[4];
#pragma unroll
            for (int e = 0; e < 4; ++e) {
                float pm = fmaxf(fmaxf(fmaxf(s[0][e], s[1][e]), fmaxf(s[2][e], s[3][e])),
                                 fmaxf(fmaxf(s[4][e], s[5][e]), fmaxf(s[6][e], s[7][e])));
                pm = fmaxf(pm, __shfl_xor(pm, 1));
                pm = fmaxf(pm, __shfl_xor(pm, 2));
                pm = fmaxf(pm, __shfl_xor(pm, 4));
                pm = fmaxf(pm, __shfl_xor(pm, 8));
                float nm = fmaxf(m_[e], pm);
                al[e] = __expf(m_[e] - nm);
                m_[e] = nm;
            }
            {
                int src = (r >> 2) << 4;
                float a0 = __shfl(al[0], src), a1 = __shfl(al[1], src);
                float a2 = __shfl(al[2], src), a3 = __shfl(al[3], src);
                float ax = (r & 1) ? a1 : a0, ay = (r & 1) ? a3 : a2;
                float aq = (r & 2) ? ay : ax;
#pragma unroll
                for (int dt = 0; dt < 4; ++dt) {
                    accz[dt][0] *= aq; accz[dt][1] *= aq;
                    accz[dt][2] *= aq; accz[dt][3] *= aq;
                }
            }

            float ps[4] = {};
#pragma unroll
            for (int ct = 0; ct < 8; ++ct) {
                float p0 = __expf(s[ct][0] - m_[0]);
                float p1 = __expf(s[ct][1] - m_[1]);
                float p2 = __expf(s[ct][2] - m_[2]);
                float p3 = __expf(s[ct][3] - m_[3]);
                ps[0] += p0; ps[1] += p1; ps[2] += p2; ps[3] += p3;
                short4v pk = { (short)f2h(p0), (short)f2h(p1),
                               (short)f2h(p2), (short)f2h(p3) };
                int kv = ct * 16 + r;
                int phys = (kv >> 5) * 32 + (((kv >> 2) & 1) << 4)
                         + (((kv >> 3) & 3) << 2) + (kv & 3);
                *(short4v*)((char*)Pt + w * 4096 + phys * 32 + g * 8) = pk;
            }

            // LAZY: per-lane partial update only (no shuffle chain here)
#pragma unroll
            for (int e = 0; e < 4; ++e)
                lsum[e] = lsum[e] * al[e] + ps[e];

            // PV: drain P writes once, issue ALL 8 tr_reads, drain once,
            // then 16 MFMAs.
            asm volatile("s_waitcnt lgkmcnt(0)" ::: "memory");
            __builtin_amdgcn_sched_barrier(0);
            U64S4 tA[4], tB[4];
#pragma unroll
            for (int ks = 0; ks < 4; ++ks) {
                unsigned base = (unsigned)(size_t)((char*)Pt + w * 4096 + ks * 1024) + l * 8;
                asm volatile("ds_read_b64_tr_b16 %0, %1" : "=v"(tA[ks].u) : "v"(base) : "memory");
                asm volatile("ds_read_b64_tr_b16 %0, %1" : "=v"(tB[ks].u) : "v"(base + 512) : "memory");
            }
            asm volatile("s_waitcnt lgkmcnt(0)" ::: "memory");
            __builtin_amdgcn_sched_barrier(0);
#pragma unroll
            for (int ks = 0; ks < 4; ++ks) {
                union { short s[8]; half8 h; } pf;
                pf.s[0] = tA[ks].s[0]; pf.s[1] = tA[ks].s[1];
                pf.s[2] = tA[ks].s[2]; pf.s[3] = tA[ks].s[3];
                pf.s[4] = tB[ks].s[0]; pf.s[5] = tB[ks].s[1];
                pf.s[6] = tB[ks].s[2]; pf.s[7] = tB[ks].s[3];
#pragma unroll
                for (int dt = 0; dt < 4; ++dt) {
                    int d = dt * 16 + r;
                    int off = d * 256 + (((ks * 4 + g) ^ (d & 15)) << 4);
                    half8 vfrag = *(const half8*)((char*)Vsc + off);
                    accz[dt] = __builtin_amdgcn_mfma_f32_16x16x32_f16(vfrag, pf.h, accz[dt], 0, 0, 0);
                }
            }

            asm volatile("s_waitcnt vmcnt(0)" ::: "memory");   // next tile staged
            __builtin_amdgcn_s_barrier();
        }

        // final cross-lane lsum reduce (moved out of the kv loop)
#pragma unroll
        for (int e = 0; e < 4; ++e) {
            float rs = lsum[e];
            rs += __shfl_xor(rs, 1); rs += __shfl_xor(rs, 2);
            rs += __shfl_xor(rs, 4); rs += __shfl_xor(rs, 8);
            lsum[e] = rs;
        }

        int src = (r >> 2) << 4;
        float l0 = __shfl(lsum[0], src), l1 = __shfl(lsum[1], src);
        float l2 = __shfl(lsum[2], src), l3 = __shfl(lsum[3], src);
        float lx = (r & 1) ? l1 : l0, ly = (r & 1) ? l3 : l2;
        float inv = 1.0f / ((r & 2) ? ly : lx);
#pragma unroll
        for (int dt = 0; dt < 4; ++dt) {
            ushort4 h4;
#pragma unroll
            for (int e = 0; e < 4; ++e)
                ((unsigned short*)&h4)[e] = f2h(accz[dt][e] * inv);
            size_t off = (qrow0 + wq0 + r) * 512 + n * 64 + dt * 16 + g * 4;
            *(ushort4*)(zh + off) = h4;
        }
    }
#undef STAGE_KV
}

// ---------------------------------------------------------------------------
// Workspace (bytes, 64 MB used):
//   0   : xh fp16 32M   -> after gemm1: zh fp16 8M (at 0)
//   32M : qk fp16 16M
//   48M : vT fp16 8M
//   56M : wcatT fp16 6M
//   62M : woT fp16 2M
// ---------------------------------------------------------------------------
extern "C" void kernel_launch(void* const* d_in, const int* in_sizes, int n_in,
                              void* d_out, int out_size, void* d_ws, size_t ws_size,
                              hipStream_t stream) {
    const float* x  = (const float*)d_in[0];
    const float* wq = (const float*)d_in[1];
    const float* wk = (const float*)d_in[2];
    const float* wv = (const float*)d_in[3];
    const float* wo = (const float*)d_in[4];
    float* out = (float*)d_out;

    char* w = (char*)d_ws;
    unsigned short* xh  = (unsigned short*)(w);
    unsigned short* zh  = (unsigned short*)(w);
    unsigned short* qk  = (unsigned short*)(w + 33554432);
    unsigned short* vT  = (unsigned short*)(w + 50331648);
    unsigned short* wcatT = (unsigned short*)(w + 58720256);
    unsigned short* woT = (unsigned short*)(w + 65011712);

    k_prep<<<dim3(17408), 256, 0, stream>>>(x, wq, wk, wv, wo, xh, wcatT, woT);
    k_gemm_qkv<<<dim3(64, 8), 256, 0, stream>>>(xh, wcatT, qk, vT);
    k_attn_mfma<<<dim3(16, NKV, BATCH), 256, 0, stream>>>(qk, vT, zh);
    k_gemm_out<<<dim3(64, 16), 256, 0, stream>>>(zh, woT, out);
}